// Round 9
// baseline (204.368 us; speedup 1.0000x reference)
//
#include <hip/hip_runtime.h>
#include <math.h>

// Problem constants
#define BATCH 4096
#define NFEAT 26
#define VOCAB 10000
#define EDIM 64
#define D0 1664          // NFEAT*EDIM
#define NUMB 13
#define IN_DIM 1677      // D0 + NUMB
#define H1D 1024
#define H2D 512
#define H3D 256
#define EPS 1e-5f

// ---------------------------------------------------------------------------
// Single mega-kernel, affine-collapse math (verified r1/r2/r4/r6/r7/r8,
// absmax 0.00195):
//   z_h[row] = x . (u0*s0) + Cv,   u2 = W3^T(pw_h*s3), u1 = W2^T(u2*s2),
//   u0 = W1^T(u1*s1), Cv = u0.t0 + u1.b1' + u2.b2' + C3.
//
// ROUND-9 SYNTHESIS of the measured failures:
//   r4: pre-gate overlap works, but L3 re-traversal costs > overlap gain.
//   r6: register capture right idea; ev[2][7]=56 regs spilled at cap 64
//       (WRITE_SIZE 0.2->6.8MB scratch).
//   r7: VGPR clamp to 32 killed load pipelining; gate-first poll storm.
// Fix: 1 row/WAVE -> capture is ev[7] = 28 VGPRs. __launch_bounds__(256,5)
// -> VGPR cap 102 (fits ~85-reg working set, no spill) and 5 blocks/CU
// -> 1280 co-resident >= 1137 grid (deadlock-impossible). Fuse blocks
// traverse BEFORE the gate (overlapping collapse); gate is already open
// when they arrive -> no poll storm window. ONE memory traversal total.
//
// Sync protocol (passed r4/r6/r7/r8): poll RELAXED + s_sleep (no L2-inv
// storm), bounded (fail-visible, never hang); acquire re-check + one
// threadfence on trip. Writers: syncthreads -> threadfence -> release add.
// Phases: bid 0..15 A(u2)->B->C; 16..63 B(u1)->C; 64..111 C(u0);
//         112 Csums+C3; 113..1136 fuse (4 rows, 1 row/wave).
//         fA(16)->B, fB(64)->C, fC(113)->fuse tail.
// ---------------------------------------------------------------------------

#define NC 113
#define NFUSE 1024
#define GRID_BLKS (NC + NFUSE)
#define TA 16
#define TB 64
#define TC 113
#define SPIN_CAP 200000

__device__ __forceinline__ void wait_flag(int* f, int target) {
    if (threadIdx.x == 0) {
        int it = 0;
        // RELAXED poll: no per-iteration cache maintenance (r2 lesson).
        while (__hip_atomic_load(f, __ATOMIC_RELAXED, __HIP_MEMORY_SCOPE_AGENT) < target) {
            __builtin_amdgcn_s_sleep(8);
            if (++it > SPIN_CAP) break;    // fail-visible, never hang
        }
        // Acquire re-check (value used -> not eliminable): one L2 inv.
        while (__hip_atomic_load(f, __ATOMIC_ACQUIRE, __HIP_MEMORY_SCOPE_AGENT) < target) {
            __builtin_amdgcn_s_sleep(8);
            if (++it > SPIN_CAP) break;
        }
        __threadfence();
    }
    __syncthreads();
}

__device__ __forceinline__ void post_flag(int* f) {
    __syncthreads();   // all block stores issued+drained
    if (threadIdx.x == 0) {
        __threadfence();   // write back this XCD's L2 to the coherent point
        __hip_atomic_fetch_add(f, 1, __ATOMIC_RELEASE, __HIP_MEMORY_SCOPE_AGENT);
    }
}

__global__ __launch_bounds__(256, 5) void mega(
    const float* __restrict__ numb, const int* __restrict__ cat,
    const float* __restrict__ emb, const float* __restrict__ bn0,
    const float* __restrict__ w1, const float* __restrict__ b1,
    const float* __restrict__ bn1,
    const float* __restrict__ w2, const float* __restrict__ b2,
    const float* __restrict__ bn2,
    const float* __restrict__ w3, const float* __restrict__ b3,
    const float* __restrict__ bn3,
    const float* __restrict__ cw, const float* __restrict__ cb,
    const float* __restrict__ pw, const float* __restrict__ pb,
    float* __restrict__ u2, float* __restrict__ u1, float* __restrict__ u0,
    float* __restrict__ Cv, int* __restrict__ flags,
    float* __restrict__ Csums, float* __restrict__ out) {
    const int bid = blockIdx.x, tid = threadIdx.x;
    int* fA = flags + 0;
    int* fB = flags + 1;
    int* fC = flags + 2;

    __shared__ __align__(16) float sA[1792];   // fuse: vj; collapse: a3s/part/a2s/a1s
    __shared__ float sRed[4][4];
    __shared__ int sIdx[4][NFEAT];

    if (bid < NC) {
        if (bid == 112) {
            // ---- Csums (cross/pred column sums) + C3 -> Cv ----  [verified]
            float p0 = 0.f, p1 = 0.f, p2 = 0.f, p3 = 0.f;
            for (int j = tid; j < D0; j += 256) {
                p0 += cw[j]; p1 += cw[D0 + j]; p2 += cw[2 * D0 + j]; p3 += pw[j];
            }
            for (int o = 32; o > 0; o >>= 1) {
                p0 += __shfl_down(p0, o, 64); p1 += __shfl_down(p1, o, 64);
                p2 += __shfl_down(p2, o, 64); p3 += __shfl_down(p3, o, 64);
            }
            if ((tid & 63) == 0) {
                int w = tid >> 6;
                sRed[w][0] = p0; sRed[w][1] = p1; sRed[w][2] = p2; sRed[w][3] = p3;
            }
            __syncthreads();
            if (tid < 4) Csums[tid] = sRed[0][tid] + sRed[1][tid] + sRed[2][tid] + sRed[3][tid];
            __syncthreads();
            float c3;
            {   // 256 threads exactly cover H3D
                const int c = tid;
                float s3 = bn3[c] * rsqrtf(bn3[3 * H3D + c] + EPS);
                c3 = pw[D0 + c] * ((b3[c] - bn3[2 * H3D + c]) * s3 + bn3[H3D + c]);
            }
            for (int o = 32; o > 0; o >>= 1) c3 += __shfl_down(c3, o, 64);
            if ((tid & 63) == 0) sRed[tid >> 6][0] = c3;
            __syncthreads();
            if (tid == 0) atomicAdd(Cv, sRed[0][0] + sRed[1][0] + sRed[2][0] + sRed[3][0]);
            post_flag(fC);
            return;
        }

        if (bid < 16) {
            // ---- phase A: u2[32*bid .. +32) owner  [verified] ----
            {
                float s3 = bn3[tid] * rsqrtf(bn3[3 * H3D + tid] + EPS);
                sA[tid] = pw[D0 + tid] * s3;          // a3s[256]
            }
            __syncthreads();
            const int kk = tid & 31, seg = tid >> 5;
            const int k = bid * 32 + kk;
            float acc = 0.f;
#pragma unroll
            for (int i = 0; i < 32; ++i) {
                int c = seg * 32 + i;
                acc += sA[c] * w3[(size_t)c * H2D + k];   // coalesced 128B runs
            }
            sA[256 + tid] = acc;                      // part[256]
            __syncthreads();
            if (tid < 32) {
                float s = 0.f;
#pragma unroll
                for (int sg = 0; sg < 8; ++sg) s += sA[256 + sg * 32 + tid];
                const int kq = bid * 32 + tid;
                u2[kq] = s;                           // owner write
                float s2 = bn2[kq] * rsqrtf(bn2[3 * H2D + kq] + EPS);
                float beta2 = (b2[kq] - bn2[2 * H2D + kq]) * s2 + bn2[H2D + kq];
                float pc = s * beta2;
                for (int o = 16; o > 0; o >>= 1) pc += __shfl_down(pc, o, 32);
                if (tid == 0) atomicAdd(Cv, pc);      // u2.beta2 contribution
            }
            post_flag(fA);
        }

        if (bid < 64) {
            // ---- phase B: u1[n] += sum_p a2[p]*W2[p,n]  [verified] ----
            wait_flag(fA, TA);
            const int p0 = (bid >> 2) * 32;
            if (tid < 32) {
                const int p = p0 + tid;
                float s2 = bn2[p] * rsqrtf(bn2[3 * H2D + p] + EPS);
                sA[1024 + tid] = u2[p] * s2;          // a2s[32]
            }
            __syncthreads();
            const int n = (bid & 3) * 256 + tid;
            float acc = 0.f;
#pragma unroll
            for (int p = 0; p < 32; ++p)
                acc += sA[1024 + p] * w2[(size_t)(p0 + p) * H1D + n];   // coalesced
            atomicAdd(&u1[n], acc);
            float s1 = bn1[n] * rsqrtf(bn1[3 * H1D + n] + EPS);
            float beta1 = (b1[n] - bn1[2 * H1D + n]) * s1 + bn1[H1D + n];
            float pc = acc * beta1;
            for (int o = 32; o > 0; o >>= 1) pc += __shfl_down(pc, o, 64);
            if ((tid & 63) == 0) sRed[tid >> 6][0] = pc;
            __syncthreads();
            if (tid == 0) atomicAdd(Cv, sRed[0][0] + sRed[1][0] + sRed[2][0] + sRed[3][0]);
            post_flag(fB);
        }

        // ---- phase C: u0[j] += sum_n a1[n]*W1[n,j]  [verified] ----
        wait_flag(fB, TB);
        const int jc = bid % 7, n0c = (bid / 7) * 64;
        if (tid < 64) {
            const int n = n0c + tid;
            float s1 = bn1[n] * rsqrtf(bn1[3 * H1D + n] + EPS);
            sA[tid] = u1[n] * s1;                     // a1s[64]
        }
        __syncthreads();
        const int j = jc * 256 + tid;
        float pc = 0.f;
        if (j < IN_DIM) {
            float acc = 0.f;
#pragma unroll 8
            for (int n = 0; n < 64; ++n)
                acc += sA[n] * w1[(size_t)(n0c + n) * IN_DIM + j];   // coalesced
            atomicAdd(&u0[j], acc);
            float s0 = bn0[j] * rsqrtf(bn0[3 * IN_DIM + j] + EPS);
            float t0 = bn0[IN_DIM + j] - bn0[2 * IN_DIM + j] * s0;
            pc = acc * t0;
        }
        for (int o = 32; o > 0; o >>= 1) pc += __shfl_down(pc, o, 64);
        if ((tid & 63) == 0) sRed[tid >> 6][0] = pc;
        __syncthreads();
        if (tid == 0) atomicAdd(Cv, sRed[0][0] + sRed[1][0] + sRed[2][0] + sRed[3][0]);
        post_flag(fC);
        return;
    }

    // ---- fuse: 4 rows/block, 1 row/WAVE; ONE gather traversal ----
    const int b0 = (bid - NC) * 4;
    if (tid < 4 * NFEAT)
        sIdx[tid / NFEAT][tid % NFEAT] = cat[(b0 + tid / NFEAT) * NFEAT + tid % NFEAT];
    __syncthreads();

    const int wave = tid >> 6, lane = tid & 63;
    const int r = wave, b = b0 + r;
    const float4* cw0 = (const float4*)cw;
    const float4* cw1 = (const float4*)(cw + D0);
    const float4* cw2 = (const float4*)(cw + 2 * D0);
    const float4* pw4 = (const float4*)pw;

    // -------- pass 1 (PRE-GATE, overlaps collapse): 4 dots + capture -----
    // ev[7] = 28 VGPRs/lane (the r6 spill was ev[2][7]=56 under cap 64;
    // here cap is 102). Fully unrolled -> static indices, stays in regs.
    float4 ev[7];
    float d0 = 0.f, d1 = 0.f, d2 = 0.f, dp = 0.f;
#pragma unroll
    for (int it = 0; it < 7; it++) {
        const int j = lane + it * 64;
        if (j < D0 / 4) {
            const int f = j >> 4, d4 = j & 15;
            const float4 v = *(const float4*)&emb[((size_t)f * VOCAB + sIdx[r][f]) * EDIM + d4 * 4];
            ev[it] = v;
            const float4 c0 = cw0[j], c1 = cw1[j], c2 = cw2[j], p4 = pw4[j];
            d0 += v.x * c0.x + v.y * c0.y + v.z * c0.z + v.w * c0.w;
            d1 += v.x * c1.x + v.y * c1.y + v.z * c1.z + v.w * c1.w;
            d2 += v.x * c2.x + v.y * c2.y + v.z * c2.z + v.w * c2.w;
            dp += v.x * p4.x + v.y * p4.y + v.z * p4.z + v.w * p4.w;
        }
    }
    for (int o = 32; o > 0; o >>= 1) {
        d0 += __shfl_down(d0, o, 64); d1 += __shfl_down(d1, o, 64);
        d2 += __shfl_down(d2, o, 64); dp += __shfl_down(dp, o, 64);
    }

    // -------- gate (open by the time traversal finishes: no poll storm) --
    wait_flag(fC, TC);

    // -------- pass 2 (POST-GATE): vj = u0*s0; dv from REGISTERS ----------
    for (int j = tid; j < IN_DIM; j += 256) {
        float s0 = bn0[j] * rsqrtf(bn0[3 * IN_DIM + j] + EPS);
        sA[j] = u0[j] * s0;                           // vj
    }
    __syncthreads();

    float dv = 0.f;
#pragma unroll
    for (int it = 0; it < 7; it++) {
        const int j = lane + it * 64;
        if (j < D0 / 4) {
            const float4 v = ev[it];
            const float4 vv = *(const float4*)&sA[j * 4];
            dv += v.x * vv.x + v.y * vv.y + v.z * vv.z + v.w * vv.w;
        }
    }
    for (int o = 32; o > 0; o >>= 1) dv += __shfl_down(dv, o, 64);

    if (lane == 0) {
        float dn = 0.f;
#pragma unroll
        for (int t = 0; t < NUMB; ++t) dn += numb[b * NUMB + t] * sA[D0 + t];
        float P = 1.f, Q = 0.f;
        float dd[3] = {d0, d1, d2};
#pragma unroll
        for (int i = 0; i < 3; i++) {
            float s = 1.f + P * dd[i] + Q * Csums[i];
            P = s * P;
            Q = s * Q + cb[i];
        }
        float z = P * dp + Q * Csums[3] + dv + dn + Cv[0] + pb[0];
        out[b] = 1.f / (1.f + expf(-z));
    }
}

// ---------------------------------------------------------------------------
extern "C" void kernel_launch(void* const* d_in, const int* in_sizes, int n_in,
                              void* d_out, int out_size, void* d_ws, size_t ws_size,
                              hipStream_t stream) {
    const float* numb = (const float*)d_in[0];
    const int* cat = (const int*)d_in[1];
    const float* emb = (const float*)d_in[2];
    const float* bn0 = (const float*)d_in[3];
    const float* w1 = (const float*)d_in[4];
    const float* b1 = (const float*)d_in[5];
    const float* bn1 = (const float*)d_in[6];
    const float* w2 = (const float*)d_in[7];
    const float* b2 = (const float*)d_in[8];
    const float* bn2 = (const float*)d_in[9];
    const float* w3 = (const float*)d_in[10];
    const float* b3 = (const float*)d_in[11];
    const float* bn3 = (const float*)d_in[12];
    const float* cw = (const float*)d_in[13];
    const float* cb = (const float*)d_in[14];
    const float* pw = (const float*)d_in[15];
    const float* pb = (const float*)d_in[16];
    float* out = (float*)d_out;

    char* ws = (char*)d_ws;
    // workspace layout (bytes):
    float* u2    = (float*)(ws + 0);      // 512 f, owner-written (no zero)
    // ---- zeroed region starts at +2048 ----
    float* u1    = (float*)(ws + 2048);   // 1024 f (atomic accumulate)
    float* u0    = (float*)(ws + 6144);   // 1792 f (atomic accumulate; 1677 used)
    float* Cv    = (float*)(ws + 13312);  // 1 f + pad (atomic accumulate)
    int*   flags = (int*)(ws + 13328);    // fA, fB, fC
    // ---- zeroed region ends at +13344 (11296 bytes) ----
    float* Csums = (float*)(ws + 13344);  // 4 f, owner-written

    // One fill node zeroes accumulators + flags (poison-proof), then ONE
    // kernel dispatch does everything.
    hipMemsetAsync(ws + 2048, 0, 11296, stream);
    mega<<<GRID_BLKS, 256, 0, stream>>>(
        numb, cat, emb, bn0, w1, b1, bn1, w2, b2, bn2, w3, b3, bn3,
        cw, cb, pw, pb, u2, u1, u0, Cv, flags, Csums, out);
}

// Round 10
// 148.008 us; speedup vs baseline: 1.3808x; 1.3808x over previous
//
#include <hip/hip_runtime.h>
#include <math.h>

// Problem constants
#define BATCH 4096
#define NFEAT 26
#define VOCAB 10000
#define EDIM 64
#define D0 1664          // NFEAT*EDIM
#define NUMB 13
#define IN_DIM 1677      // D0 + NUMB
#define H1D 1024
#define H2D 512
#define H3D 256
#define EPS 1e-5f

// ---------------------------------------------------------------------------
// ROUND-10: back to the PROVEN round-1 structure (150.0us, best measured),
// 4 dispatches, no flags, no memset; ONLY fuse_out is changed.
//
// Ledger (rounds 2-9): total =~ kernel_time + ~115us harness floor.
//   r1  4-dispatch, fuse 512blk x 2rows/wave:        150.0  (kernels ~35)
//   r2-r9 mega/gate variants:                        192-298 (kernels 77-187)
// r9 postmortem: compiler REMATERIALIZED post-gate emb loads (VGPR=40, no
// spill) -> two traversals; register capture across a gate is uncompilable.
// The only remaining lever: faster single-traversal fuse.
//
// New fuse_out: 1 row/WAVE, 1024 blocks (4 blocks/CU -> ~16 waves/CU, 2x
// r1's concurrent gather streams; whole grid resident), j-loop fully
// unrolled to 7 predicated iterations -> all emb/weight loads issue
// back-to-back (no VGPR clamp). Per-lane accumulation order identical to
// r1 -> absmax bit-identical (0.001953125).
//
// Affine-collapse math (verified r1/r2/r4/r6/r7/r8/r9):
//   z_h[row] = x . (u0*s0) + Cv,   u2 = W3^T(pw_h*s3), u1 = W2^T(u2*s2),
//   u0 = W1^T(u1*s1), Cv = u0.t0 + u1.b1' + u2.b2' + C3.
// ---------------------------------------------------------------------------

// ---------------------------------------------------------------------------
// collapseA: blocks 0..15 each OWN k-range [bid*32, +32) of u2; block 16:
// Csums + C3. ALL blocks redundantly zero the u1/u0/Cv region.  [r1 verbatim]
// ---------------------------------------------------------------------------
__global__ __launch_bounds__(256) void collapseA(
    const float* __restrict__ w3, const float* __restrict__ b3,
    const float* __restrict__ bn3, const float* __restrict__ pw,
    const float* __restrict__ b2, const float* __restrict__ bn2,
    const float* __restrict__ cw,
    float* __restrict__ u2, float* __restrict__ CvA,
    float* __restrict__ C3s, float* __restrict__ Csums,
    float* __restrict__ zero_region) {
    const int bid = blockIdx.x, tid = threadIdx.x;
    __shared__ float a3s[H3D];
    __shared__ float part[256];
    __shared__ float red[4][4];

    for (int i = tid; i < 2817; i += 256) zero_region[i] = 0.f;

    if (bid < 16) {
        {   // stage a3 = pw_h * s3
            const int c = tid;
            float s3 = bn3[c] * rsqrtf(bn3[3 * H3D + c] + EPS);
            a3s[c] = pw[D0 + c] * s3;
        }
        __syncthreads();
        const int kk = tid & 31, seg = tid >> 5;
        const int k = bid * 32 + kk;
        float acc = 0.f;
#pragma unroll
        for (int i = 0; i < 32; ++i) {
            int c = seg * 32 + i;
            acc += a3s[c] * w3[(size_t)c * H2D + k];   // coalesced
        }
        part[tid] = acc;
        __syncthreads();
        if (tid < 32) {
            float s = 0.f;
#pragma unroll
            for (int sg = 0; sg < 8; ++sg) s += part[sg * 32 + tid];
            const int kq = bid * 32 + tid;
            u2[kq] = s;                                // owner write
            float s2 = bn2[kq] * rsqrtf(bn2[3 * H2D + kq] + EPS);
            float beta2 = (b2[kq] - bn2[2 * H2D + kq]) * s2 + bn2[H2D + kq];
            float pc = s * beta2;
            for (int o = 16; o > 0; o >>= 1) pc += __shfl_down(pc, o, 32);
            if (tid == 0) CvA[bid] = pc;
        }
    } else {
        // block 16: Csums + C3
        float p0 = 0.f, p1 = 0.f, p2 = 0.f, p3 = 0.f;
        for (int j = tid; j < D0; j += 256) {
            p0 += cw[j]; p1 += cw[D0 + j]; p2 += cw[2 * D0 + j]; p3 += pw[j];
        }
        for (int o = 32; o > 0; o >>= 1) {
            p0 += __shfl_down(p0, o, 64); p1 += __shfl_down(p1, o, 64);
            p2 += __shfl_down(p2, o, 64); p3 += __shfl_down(p3, o, 64);
        }
        if ((tid & 63) == 0) {
            int w = tid >> 6;
            red[w][0] = p0; red[w][1] = p1; red[w][2] = p2; red[w][3] = p3;
        }
        __syncthreads();
        if (tid < 4) Csums[tid] = red[0][tid] + red[1][tid] + red[2][tid] + red[3][tid];
        __syncthreads();
        float c3;
        {
            const int c = tid;
            float s3 = bn3[c] * rsqrtf(bn3[3 * H3D + c] + EPS);
            c3 = pw[D0 + c] * ((b3[c] - bn3[2 * H3D + c]) * s3 + bn3[H3D + c]);
        }
        for (int o = 32; o > 0; o >>= 1) c3 += __shfl_down(c3, o, 64);
        if ((tid & 63) == 0) red[tid >> 6][0] = c3;
        __syncthreads();
        if (tid == 0) C3s[0] = red[0][0] + red[1][0] + red[2][0] + red[3][0];
    }
}

// ---------------------------------------------------------------------------
// collapseB: 64 blocks = (n-chunk 4 x 256) x (p-chunk 16 x 32).  [r1 verbatim]
// ---------------------------------------------------------------------------
__global__ __launch_bounds__(256) void collapseB(
    const float* __restrict__ w2, const float* __restrict__ bn2,
    const float* __restrict__ u2,
    const float* __restrict__ b1, const float* __restrict__ bn1,
    const float* __restrict__ CvA, const float* __restrict__ C3s,
    float* __restrict__ u1, float* __restrict__ Cv) {
    const int bid = blockIdx.x, tid = threadIdx.x;
    __shared__ float a2s[32];
    __shared__ float red[4];
    const int p0 = (bid >> 2) * 32;
    if (tid < 32) {
        const int p = p0 + tid;
        float s2 = bn2[p] * rsqrtf(bn2[3 * H2D + p] + EPS);
        a2s[tid] = u2[p] * s2;
    }
    __syncthreads();
    const int n = (bid & 3) * 256 + tid;
    float acc = 0.f;
#pragma unroll
    for (int p = 0; p < 32; ++p)
        acc += a2s[p] * w2[(size_t)(p0 + p) * H1D + n];   // coalesced
    atomicAdd(&u1[n], acc);
    float s1 = bn1[n] * rsqrtf(bn1[3 * H1D + n] + EPS);
    float beta1 = (b1[n] - bn1[2 * H1D + n]) * s1 + bn1[H1D + n];
    float pc = acc * beta1;
    for (int o = 32; o > 0; o >>= 1) pc += __shfl_down(pc, o, 64);
    if ((tid & 63) == 0) red[tid >> 6] = pc;
    __syncthreads();
    if (tid == 0) atomicAdd(Cv, red[0] + red[1] + red[2] + red[3]);
    if (bid == 0 && tid < 16) {
        float v = CvA[tid];
        for (int o = 8; o > 0; o >>= 1) v += __shfl_down(v, o, 16);
        if (tid == 0) atomicAdd(Cv, v + C3s[0]);
    }
}

// ---------------------------------------------------------------------------
// collapseC: 112 blocks = (j-chunk 7 x 256) x (n-chunk 16 x 64). [r1 verbatim]
// ---------------------------------------------------------------------------
__global__ __launch_bounds__(256) void collapseC(
    const float* __restrict__ w1, const float* __restrict__ bn1,
    const float* __restrict__ u1, const float* __restrict__ bn0,
    float* __restrict__ u0, float* __restrict__ Cv) {
    const int bid = blockIdx.x, tid = threadIdx.x;
    __shared__ float a1s[64];
    __shared__ float red[4];
    const int jc = bid % 7, n0 = (bid / 7) * 64;
    if (tid < 64) {
        const int n = n0 + tid;
        float s1 = bn1[n] * rsqrtf(bn1[3 * H1D + n] + EPS);
        a1s[tid] = u1[n] * s1;
    }
    __syncthreads();
    const int j = jc * 256 + tid;
    float pc = 0.f;
    if (j < IN_DIM) {
        float acc = 0.f;
#pragma unroll 8
        for (int n = 0; n < 64; ++n)
            acc += a1s[n] * w1[(size_t)(n0 + n) * IN_DIM + j];   // coalesced
        atomicAdd(&u0[j], acc);
        float s0 = bn0[j] * rsqrtf(bn0[3 * IN_DIM + j] + EPS);
        float t0 = bn0[IN_DIM + j] - bn0[2 * IN_DIM + j] * s0;
        pc = acc * t0;
    }
    for (int o = 32; o > 0; o >>= 1) pc += __shfl_down(pc, o, 64);
    if ((tid & 63) == 0) red[tid >> 6] = pc;
    __syncthreads();
    if (tid == 0) atomicAdd(Cv, red[0] + red[1] + red[2] + red[3]);
}

// ---------------------------------------------------------------------------
// fuse_out (the ONLY change vs r1): 1024 blocks x 4 rows, 1 row/WAVE.
// 2x r1's concurrent gather streams (4 blocks/CU, whole grid resident);
// j-loop fully unrolled to 7 predicated iterations -> max loads in flight.
// Per-lane j-sequence and accumulation order identical to r1.
// ---------------------------------------------------------------------------
__global__ __launch_bounds__(256) void fuse_out(
    const float* __restrict__ numb, const int* __restrict__ cat,
    const float* __restrict__ emb, const float* __restrict__ bn0,
    const float* __restrict__ cw, const float* __restrict__ cb,
    const float* __restrict__ pw, const float* __restrict__ pb,
    const float* __restrict__ u0, const float* __restrict__ Cv,
    const float* __restrict__ Csums, float* __restrict__ out) {
    __shared__ __align__(16) float vj[IN_DIM + 3];
    __shared__ int idx[4][NFEAT];
    const int bid = blockIdx.x, tid = threadIdx.x;
    const int b0 = bid * 4;

    for (int j = tid; j < IN_DIM; j += 256) {
        float s0 = bn0[j] * rsqrtf(bn0[3 * IN_DIM + j] + EPS);
        vj[j] = u0[j] * s0;
    }
    if (tid < 4 * NFEAT)
        idx[tid / NFEAT][tid % NFEAT] = cat[(b0 + tid / NFEAT) * NFEAT + tid % NFEAT];
    __syncthreads();

    const int wave = tid >> 6, lane = tid & 63;
    const int r = wave, b = b0 + wave;
    const float4* cw0 = (const float4*)cw;
    const float4* cw1 = (const float4*)(cw + D0);
    const float4* cw2 = (const float4*)(cw + 2 * D0);
    const float4* pw4 = (const float4*)pw;

    float d0 = 0.f, d1 = 0.f, d2 = 0.f, dp = 0.f, dv = 0.f;
#pragma unroll
    for (int it = 0; it < 7; it++) {
        const int j = lane + it * 64;
        if (j < D0 / 4) {
            const int f = j >> 4, d4 = j & 15;
            const float4 v = *(const float4*)&emb[((size_t)f * VOCAB + idx[r][f]) * EDIM + d4 * 4];
            const float4 c0 = cw0[j], c1 = cw1[j], c2 = cw2[j], p4 = pw4[j];
            const float4 vv = *(const float4*)&vj[j * 4];
            d0 += v.x * c0.x + v.y * c0.y + v.z * c0.z + v.w * c0.w;
            d1 += v.x * c1.x + v.y * c1.y + v.z * c1.z + v.w * c1.w;
            d2 += v.x * c2.x + v.y * c2.y + v.z * c2.z + v.w * c2.w;
            dp += v.x * p4.x + v.y * p4.y + v.z * p4.z + v.w * p4.w;
            dv += v.x * vv.x + v.y * vv.y + v.z * vv.z + v.w * vv.w;
        }
    }
    for (int o = 32; o > 0; o >>= 1) {
        d0 += __shfl_down(d0, o, 64); d1 += __shfl_down(d1, o, 64);
        d2 += __shfl_down(d2, o, 64); dp += __shfl_down(dp, o, 64);
        dv += __shfl_down(dv, o, 64);
    }
    if (lane == 0) {
        float dn = 0.f;
#pragma unroll
        for (int t = 0; t < NUMB; ++t) dn += numb[b * NUMB + t] * vj[D0 + t];
        float P = 1.f, Q = 0.f;
        float dd[3] = {d0, d1, d2};
#pragma unroll
        for (int i = 0; i < 3; i++) {
            float s = 1.f + P * dd[i] + Q * Csums[i];
            P = s * P;
            Q = s * Q + cb[i];
        }
        float z = P * dp + Q * Csums[3] + dv + dn + Cv[0] + pb[0];
        out[b] = 1.f / (1.f + expf(-z));
    }
}

// ---------------------------------------------------------------------------
extern "C" void kernel_launch(void* const* d_in, const int* in_sizes, int n_in,
                              void* d_out, int out_size, void* d_ws, size_t ws_size,
                              hipStream_t stream) {
    const float* numb = (const float*)d_in[0];
    const int* cat = (const int*)d_in[1];
    const float* emb = (const float*)d_in[2];
    const float* bn0 = (const float*)d_in[3];
    const float* w1 = (const float*)d_in[4];
    const float* b1 = (const float*)d_in[5];
    const float* bn1 = (const float*)d_in[6];
    const float* w2 = (const float*)d_in[7];
    const float* b2 = (const float*)d_in[8];
    const float* bn2 = (const float*)d_in[9];
    const float* w3 = (const float*)d_in[10];
    const float* b3 = (const float*)d_in[11];
    const float* bn3 = (const float*)d_in[12];
    const float* cw = (const float*)d_in[13];
    const float* cb = (const float*)d_in[14];
    const float* pw = (const float*)d_in[15];
    const float* pb = (const float*)d_in[16];
    float* out = (float*)d_out;

    char* ws = (char*)d_ws;
    float* u2    = (float*)(ws + 0);      // 512 f  (owner-written)
    float* u1    = (float*)(ws + 2048);   // 1024 f (atomic; zeroed by A)
    float* u0    = (float*)(ws + 6144);   // 1792 f (atomic; zeroed by A)
    float* Cv    = (float*)(ws + 13312);  // 1 f    (atomic; zeroed by A)
    float* CvA   = (float*)(ws + 13376);  // 16 f   (direct-written by A)
    float* C3s   = (float*)(ws + 13440);  // 1 f    (direct-written by A)
    float* Csums = (float*)(ws + 13456);  // 4 f    (direct-written by A)
    float* zero_region = u1;              // floats [512,3329) = 2817

    collapseA<<<17, 256, 0, stream>>>(w3, b3, bn3, pw, b2, bn2, cw,
                                      u2, CvA, C3s, Csums, zero_region);
    collapseB<<<64, 256, 0, stream>>>(w2, bn2, u2, b1, bn1, CvA, C3s, u1, Cv);
    collapseC<<<112, 256, 0, stream>>>(w1, bn1, u1, bn0, u0, Cv);
    fuse_out<<<1024, 256, 0, stream>>>(numb, cat, emb, bn0, cw, cb, pw, pb,
                                       u0, Cv, Csums, out);
}